// Round 4
// baseline (206.247 us; speedup 1.0000x reference)
//
#include <hip/hip_runtime.h>
#include <hip/hip_bf16.h>
#include <math.h>

#define P_N   2048
#define B_N   10000
#define NB    15
#define MROWS (P_N * NB)   // 30720
#define SPLIT 5
#define BPB   (B_N / SPLIT)  // 2000 boundary points per scan block

typedef __bf16 bf16x8 __attribute__((ext_vector_type(8)));
typedef float  f32x4  __attribute__((ext_vector_type(4)));

__device__ __forceinline__ float bf2f(unsigned short u) {
    union { unsigned int i; float f; } v; v.i = ((unsigned int)u) << 16; return v.f;
}
__device__ __forceinline__ unsigned short f2bf(float f) {
    union { float f; unsigned int i; } v; v.f = f;
    unsigned int i = v.i;
    i += 0x7FFFu + ((i >> 16) & 1u);
    return (unsigned short)(i >> 16);
}
__device__ __forceinline__ void gld_lds16(const unsigned short* g, unsigned short* l) {
    __builtin_amdgcn_global_load_lds(
        (const __attribute__((address_space(1))) unsigned int*)g,
        (__attribute__((address_space(3))) unsigned int*)l, 16, 0, 0);
}

// ---- K0: tiled transpose W1/W2 -> bf16 [N][K]; zero stats; init keys --------
__global__ __launch_bounds__(256) void k_prep(const float* __restrict__ W1,
        const float* __restrict__ W2, unsigned short* __restrict__ w1t,
        unsigned short* __restrict__ w2t, float* __restrict__ stats,
        unsigned long long* __restrict__ keys) {
    int blk = blockIdx.x, tid = threadIdx.x;
    if (blk < 144) {
        __shared__ unsigned short t[64][65];
        const float* W; unsigned short* O; int NC, K, tr, tc;
        if (blk < 16) { W = W1; O = w1t; NC = 512; K = 128; tr = blk & 1; tc = blk >> 1; }
        else { int b = blk - 16; W = W2; O = w2t; NC = 1024; K = 512; tr = b & 7; tc = b >> 3; }
        int r0 = tr * 64, c0 = tc * 64;
        int cx = tid & 63, rg = tid >> 6;
#pragma unroll
        for (int i = 0; i < 16; ++i) {
            int r = rg * 16 + i;
            t[r][cx] = f2bf(W[(size_t)(r0 + r) * NC + c0 + cx]);
        }
        __syncthreads();
#pragma unroll
        for (int i = 0; i < 16; ++i) {
            int n = rg * 16 + i;
            O[(size_t)(c0 + n) * K + r0 + cx] = t[cx][n];
        }
    } else {
        int idx = (blk - 144) * 256 + tid;        // 120 blocks: 30720 keys
        if (idx < MROWS) keys[idx] = ~0ull;
        if (idx < 3072) stats[idx] = 0.0f;
    }
}

// ---- K1a: scan boundary points, per-bin min via packed u64 atomicMin --------
__global__ __launch_bounds__(256) void k_scan(
        const float* __restrict__ end_pos, const float* __restrict__ rel_pos,
        const float* __restrict__ bpts, unsigned long long* __restrict__ keys) {
    __shared__ unsigned long long s_key[NB];
    int tid = threadIdx.x;
    int p = blockIdx.x / SPLIT, part = blockIdx.x % SPLIT;
    if (tid < NB) s_key[tid] = ~0ull;
    __syncthreads();

    float ex = end_pos[2 * p], ey = end_pos[2 * p + 1];
    float rx = rel_pos[2 * p], ry = rel_pos[2 * p + 1];
    float rr = rx * rx + ry * ry;
    float c, s;
    if (rr > 0.0f) { float inv = 1.0f / sqrtf(rr); c = rx * inv; s = ry * inv; }
    else           { c = 1.0f; s = 0.0f; }

    const float T0 = -4.704630109f, T1 = -2.246036774f, T2 = -1.376381920f,
                T3 = -0.900404044f, T4 = -0.577350269f, T5 = -0.324919696f,
                T6 = -0.105104235f, T7 =  0.105104235f, T8 =  0.324919696f,
                T9 =  0.577350269f, T10 = 0.900404044f, T11 = 1.376381920f,
                T12 = 2.246036774f, T13 = 4.704630109f;

    const float2* bp2 = (const float2*)bpts;
    int bstart = part * BPB;
    for (int b = bstart + tid; b < bstart + BPB; b += 256) {
        float2 pt = bp2[b];
        float dx = pt.x - ex, dy = pt.y - ey;
        float xb = dx * c + dy * s;
        float yb = dy * c - dx * s;
        float r2 = xb * xb + yb * yb;
        bool v3 = yb > T7 * xb;
        float ta = v3 ? T11 : T3;
        bool v2 = yb > ta * xb;
        float tb = v3 ? (v2 ? T13 : T9) : (v2 ? T5 : T1);
        bool v1 = yb > tb * xb;
        float tc = v3 ? (v2 ? (v1 ? 3.0e38f : T12) : (v1 ? T10 : T8))
                      : (v2 ? (v1 ? T6 : T4)       : (v1 ? T2 : T0));
        bool v0 = yb > tc * xb;
        int bin = (v3 ? 8 : 0) + (v2 ? 4 : 0) + (v1 ? 2 : 0) + (v0 ? 1 : 0);
        if (xb > 0.0f) {
            unsigned long long key =
                ((unsigned long long)__float_as_uint(r2) << 32) | (unsigned int)b;
            atomicMin(&s_key[bin], key);
        }
    }
    __syncthreads();
    if (tid < NB) atomicMin(&keys[p * NB + tid], s_key[tid]);
}

// ---- K1b: choose point/fallback, build X = [emb(64) | h(64)] per (p,cell) ---
__global__ __launch_bounds__(256) void k_assemble(
        const unsigned long long* __restrict__ keys,
        const float* __restrict__ end_pos, const float* __restrict__ rel_pos,
        const float* __restrict__ bpts, const float* __restrict__ Wsp,
        const float* __restrict__ bsp, const float* __restrict__ h,
        unsigned short* __restrict__ X) {
    __shared__ float2 s_rel[NB];
    int p = blockIdx.x, tid = threadIdx.x;
    if (tid < NB) {
        float ex = end_pos[2 * p], ey = end_pos[2 * p + 1];
        unsigned long long key = keys[p * NB + tid];
        float r = sqrtf(__uint_as_float((unsigned int)(key >> 32)));
        float relx, rely;
        if (r <= 2.0f) {
            int b = (int)(key & 0xFFFFFFFFu);
            relx = bpts[2 * b] - ex; rely = bpts[2 * b + 1] - ey;
        } else {
            float rx = rel_pos[2 * p], ry = rel_pos[2 * p + 1];
            float rr = rx * rx + ry * ry;
            float c, s;
            if (rr > 0.0f) { float inv = 1.0f / sqrtf(rr); c = rx * inv; s = ry * inv; }
            else           { c = 1.0f; s = 0.0f; }
            float th = ((float)tid + 0.5f) * (float)(M_PI / 15.0) - (float)(M_PI / 2.0);
            float xc = 2.0f * cosf(th), yc = 2.0f * sinf(th);
            relx = xc * c - yc * s;
            rely = xc * s + yc * c;
        }
        s_rel[tid] = make_float2(relx, rely);
    }
    __syncthreads();
    if (tid < NB * 16) {
        int cell = tid >> 4, e0 = (tid & 15) * 8;
        float2 rel = s_rel[cell];
        unsigned short ubuf[8];
        if (e0 < 64) {
            float4 w0a = *(const float4*)(Wsp + e0),      w0b = *(const float4*)(Wsp + e0 + 4);
            float4 w1a = *(const float4*)(Wsp + 64 + e0), w1b = *(const float4*)(Wsp + 64 + e0 + 4);
            float4 bba = *(const float4*)(bsp + e0),      bbb = *(const float4*)(bsp + e0 + 4);
            float w0[8] = {w0a.x,w0a.y,w0a.z,w0a.w,w0b.x,w0b.y,w0b.z,w0b.w};
            float w1[8] = {w1a.x,w1a.y,w1a.z,w1a.w,w1b.x,w1b.y,w1b.z,w1b.w};
            float bb[8] = {bba.x,bba.y,bba.z,bba.w,bbb.x,bbb.y,bbb.z,bbb.w};
#pragma unroll
            for (int j = 0; j < 8; ++j)
                ubuf[j] = f2bf(rel.x * w0[j] + rel.y * w1[j] + bb[j]);
        } else {
            float4 ha = *(const float4*)(h + p * 64 + (e0 - 64));
            float4 hb = *(const float4*)(h + p * 64 + (e0 - 64) + 4);
            float hv[8] = {ha.x,ha.y,ha.z,ha.w,hb.x,hb.y,hb.z,hb.w};
#pragma unroll
            for (int j = 0; j < 8; ++j) ubuf[j] = f2bf(hv[j]);
        }
        *(uint4*)(X + ((size_t)p * NB + cell) * 128 + e0) = *(uint4*)ubuf;
    }
}

// ---- m97-style GEMM: C = A @ Bt^T + bias, gload_lds staging, LDS epilogue ---
template<bool STATS>
__global__ __launch_bounds__(256) void k_gemm(
        const unsigned short* __restrict__ A, const unsigned short* __restrict__ Bt,
        const float* __restrict__ bias, unsigned short* __restrict__ C,
        int M, int N, int K, float* __restrict__ osum, float* __restrict__ osq) {
    __shared__ __align__(16) unsigned short lds[8704];   // A:4096 | B:4096 ; C-epi:8704
    unsigned short* ldsA = lds;
    unsigned short* ldsB = lds + 4096;
    unsigned short* ldsC = lds;

    int tid = threadIdx.x;
    int tiles_m = M >> 7;
    int bm = blockIdx.x % tiles_m, bn = blockIdx.x / tiles_m;
    int row0 = bm << 7, col0 = bn << 7;
    int lane = tid & 63, wave = tid >> 6;
    int wr = wave >> 1, wc = wave & 1;
    int frow = lane & 15, fkb = (lane >> 4) << 3;

    f32x4 zero = {0.f, 0.f, 0.f, 0.f};
    f32x4 acc[4][4];
#pragma unroll
    for (int i = 0; i < 4; ++i)
#pragma unroll
        for (int j = 0; j < 4; ++j) acc[i][j] = zero;

    // staging: wave w covers rows [w*32, w*32+32) in two 16-row (1KB) chunks
    const unsigned short* gA = A  + (size_t)(row0 + wave * 32 + (lane >> 2)) * K + (lane & 3) * 8;
    const unsigned short* gB = Bt + (size_t)(col0 + wave * 32 + (lane >> 2)) * K + (lane & 3) * 8;
    unsigned short* lA0 = &ldsA[(wave * 32) * 32];
    unsigned short* lA1 = &ldsA[(wave * 32 + 16) * 32];
    unsigned short* lB0 = &ldsB[(wave * 32) * 32];
    unsigned short* lB1 = &ldsB[(wave * 32 + 16) * 32];

    for (int k0 = 0; k0 < K; k0 += 32) {
        __syncthreads();
        gld_lds16(gA + k0, lA0);
        gld_lds16(gA + k0 + (size_t)16 * K, lA1);
        gld_lds16(gB + k0, lB0);
        gld_lds16(gB + k0 + (size_t)16 * K, lB1);
        __syncthreads();
        bf16x8 af[4], bfv[4];
#pragma unroll
        for (int i = 0; i < 4; ++i) {
            af[i]  = *(const bf16x8*)&ldsA[(wr * 64 + i * 16 + frow) * 32 + fkb];
            bfv[i] = *(const bf16x8*)&ldsB[(wc * 64 + i * 16 + frow) * 32 + fkb];
        }
#pragma unroll
        for (int i = 0; i < 4; ++i)
#pragma unroll
            for (int j = 0; j < 4; ++j)
                acc[i][j] = __builtin_amdgcn_mfma_f32_16x16x32_bf16(af[i], bfv[j], acc[i][j], 0, 0, 0);
    }

    // epilogue: two 64-row bands; stage f2bf(acc+bias) in LDS, store coalesced
    int rbase = (lane >> 4) << 2;
#pragma unroll
    for (int ci = 0; ci < 2; ++ci) {
        __syncthreads();
        if (wr == ci) {
#pragma unroll
            for (int j = 0; j < 4; ++j) {
                int col = col0 + wc * 64 + j * 16 + frow;
                float bv = bias[col];
                float csum = 0.f, csq = 0.f;
#pragma unroll
                for (int i = 0; i < 4; ++i) {
#pragma unroll
                    for (int r = 0; r < 4; ++r) {
                        float y = acc[i][j][r] + bv;
                        ldsC[(i * 16 + rbase + r) * 136 + wc * 64 + j * 16 + frow] = f2bf(y);
                        if (STATS) { csum += y; csq = fmaf(y, y, csq); }
                    }
                }
                if (STATS) {
                    csum += __shfl_xor(csum, 16); csum += __shfl_xor(csum, 32);
                    csq  += __shfl_xor(csq, 16);  csq  += __shfl_xor(csq, 32);
                    if (lane < 16) { atomicAdd(&osum[col], csum); atomicAdd(&osq[col], csq); }
                }
            }
        }
        __syncthreads();
#pragma unroll
        for (int it = 0; it < 4; ++it) {
            int t = it * 256 + tid;
            int brow = t >> 4, seg = t & 15;
            *(uint4*)(C + (size_t)(row0 + ci * 64 + brow) * N + col0 + seg * 8) =
                *(const uint4*)&ldsC[brow * 136 + seg * 8];
        }
    }
}

// ---- finalize: per-column affine coefficients -------------------------------
__global__ void k_finalize(const float* __restrict__ s, const float* __restrict__ q,
                           const float* __restrict__ g, const float* __restrict__ be,
                           float* __restrict__ sc, float* __restrict__ sh, int Ncols) {
    int i = blockIdx.x * 256 + threadIdx.x;
    if (i >= Ncols) return;
    const float invN = 1.0f / (float)MROWS;
    float m = s[i] * invN;
    float v = q[i] * invN - m * m;
    float k = g[i] * rsqrtf(v + 1e-5f);
    sc[i] = k;
    sh[i] = be[i] - m * k;
}

// ---- BN + ReLU, in place, column-resident streaming (N=512) -----------------
__global__ __launch_bounds__(256) void k_bnrelu(unsigned short* __restrict__ Y,
        const float* __restrict__ sc, const float* __restrict__ sh) {
    int tid = threadIdx.x;
    int seg  = tid & 63;                 // 64 uint4 segments per 512-col row
    int roff = tid >> 6;                 // 4 row-phases
    int r0 = blockIdx.x * 32;
    float4 sc0 = *(const float4*)(sc + seg * 8);
    float4 sc1 = *(const float4*)(sc + seg * 8 + 4);
    float4 sh0 = *(const float4*)(sh + seg * 8);
    float4 sh1 = *(const float4*)(sh + seg * 8 + 4);
    float scv[8] = {sc0.x, sc0.y, sc0.z, sc0.w, sc1.x, sc1.y, sc1.z, sc1.w};
    float shv[8] = {sh0.x, sh0.y, sh0.z, sh0.w, sh1.x, sh1.y, sh1.z, sh1.w};
    for (int r = r0 + roff; r < r0 + 32; r += 4) {
        unsigned short* p = Y + (size_t)r * 512 + seg * 8;
        uint4 v = *(const uint4*)p;
        unsigned short* u = (unsigned short*)&v;
#pragma unroll
        for (int j = 0; j < 8; ++j) {
            float x = fmaf(bf2f(u[j]), scv[j], shv[j]);
            u[j] = f2bf(fmaxf(x, 0.0f));
        }
        *(uint4*)p = v;
    }
}

// ---- BN2 (inline coeffs) + ReLU + max over 15 cells -> out (f32) ------------
__global__ void k_bnmax(const unsigned short* __restrict__ Y2, const float* __restrict__ s2,
                        const float* __restrict__ q2, const float* __restrict__ g2,
                        const float* __restrict__ be2, float* __restrict__ out) {
    int idx = blockIdx.x * 256 + threadIdx.x;      // 2048*128 threads
    int p = idx >> 7, cb = idx & 127;
    int c0 = cb << 3;
    const float invN = 1.0f / (float)MROWS;
    float4 sa = *(const float4*)(s2 + c0),  sb = *(const float4*)(s2 + c0 + 4);
    float4 qa = *(const float4*)(q2 + c0),  qb = *(const float4*)(q2 + c0 + 4);
    float4 ga = *(const float4*)(g2 + c0),  gb = *(const float4*)(g2 + c0 + 4);
    float4 ea = *(const float4*)(be2 + c0), eb = *(const float4*)(be2 + c0 + 4);
    float sv[8] = {sa.x,sa.y,sa.z,sa.w,sb.x,sb.y,sb.z,sb.w};
    float qv[8] = {qa.x,qa.y,qa.z,qa.w,qb.x,qb.y,qb.z,qb.w};
    float gv[8] = {ga.x,ga.y,ga.z,ga.w,gb.x,gb.y,gb.z,gb.w};
    float ev[8] = {ea.x,ea.y,ea.z,ea.w,eb.x,eb.y,eb.z,eb.w};
    float scv[8], shv[8];
#pragma unroll
    for (int j = 0; j < 8; ++j) {
        float m = sv[j] * invN;
        float v = qv[j] * invN - m * m;
        float k = gv[j] * rsqrtf(v + 1e-5f);
        scv[j] = k; shv[j] = ev[j] - m * k;
    }
    float mx[8];
#pragma unroll
    for (int j = 0; j < 8; ++j) mx[j] = -3.0e38f;
#pragma unroll
    for (int cell = 0; cell < NB; ++cell) {
        uint4 v = *(const uint4*)(Y2 + ((size_t)(p * NB + cell)) * 1024 + c0);
        const unsigned short* u = (const unsigned short*)&v;
#pragma unroll
        for (int j = 0; j < 8; ++j) {
            float x = fmaf(bf2f(u[j]), scv[j], shv[j]);
            mx[j] = fmaxf(mx[j], x);
        }
    }
    float4 o0, o1;
    o0.x = fmaxf(mx[0], 0.f); o0.y = fmaxf(mx[1], 0.f);
    o0.z = fmaxf(mx[2], 0.f); o0.w = fmaxf(mx[3], 0.f);
    o1.x = fmaxf(mx[4], 0.f); o1.y = fmaxf(mx[5], 0.f);
    o1.z = fmaxf(mx[6], 0.f); o1.w = fmaxf(mx[7], 0.f);
    *(float4*)(out + (size_t)p * 1024 + c0)     = o0;
    *(float4*)(out + (size_t)p * 1024 + c0 + 4) = o1;
}

extern "C" void kernel_launch(void* const* d_in, const int* in_sizes, int n_in,
                              void* d_out, int out_size, void* d_ws, size_t ws_size,
                              hipStream_t stream) {
    const float* h       = (const float*)d_in[0];
    const float* end_pos = (const float*)d_in[1];
    const float* rel_pos = (const float*)d_in[2];
    const float* bpts    = (const float*)d_in[3];
    const float* Wsp     = (const float*)d_in[4];
    const float* bsp     = (const float*)d_in[5];
    const float* W1      = (const float*)d_in[6];
    const float* b1      = (const float*)d_in[7];
    const float* g1      = (const float*)d_in[8];
    const float* be1     = (const float*)d_in[9];
    const float* W2      = (const float*)d_in[10];
    const float* b2      = (const float*)d_in[11];
    const float* g2      = (const float*)d_in[12];
    const float* be2     = (const float*)d_in[13];
    float* out = (float*)d_out;

    char* ws = (char*)d_ws;
    float* s1  = (float*)ws;                 // zeroed by k_prep (first 3072 f32)
    float* q1  = s1 + 512;
    float* s2  = q1 + 512;
    float* q2  = s2 + 1024;
    float* sc1 = q2 + 1024;                  // written by k_finalize
    float* sh1 = sc1 + 512;
    unsigned long long* keys = (unsigned long long*)(ws + 32768);  // [30720] u64
    unsigned short* w1t = (unsigned short*)(ws + 32768 + 245760);  // [512][128]
    unsigned short* w2t = w1t + (size_t)512 * 128;                 // [1024][512]
    unsigned short* X   = w2t + (size_t)1024 * 512;                // [30720][128]
    unsigned short* Y1  = X   + (size_t)MROWS * 128;               // [30720][512]
    unsigned short* Y2  = Y1  + (size_t)MROWS * 512;               // [30720][1024]

    k_prep<<<264, 256, 0, stream>>>(W1, W2, w1t, w2t, s1, keys);
    k_scan<<<P_N * SPLIT, 256, 0, stream>>>(end_pos, rel_pos, bpts, keys);
    k_assemble<<<P_N, 256, 0, stream>>>(keys, end_pos, rel_pos, bpts, Wsp, bsp, h, X);
    k_gemm<true><<<(MROWS / 128) * (512 / 128), 256, 0, stream>>>(
        X, w1t, b1, Y1, MROWS, 512, 128, s1, q1);
    k_finalize<<<2, 256, 0, stream>>>(s1, q1, g1, be1, sc1, sh1, 512);
    k_bnrelu<<<MROWS / 32, 256, 0, stream>>>(Y1, sc1, sh1);
    k_gemm<true><<<(MROWS / 128) * (1024 / 128), 256, 0, stream>>>(
        Y1, w2t, b2, Y2, MROWS, 1024, 512, s2, q2);
    k_bnmax<<<(P_N * 128) / 256, 256, 0, stream>>>(Y2, s2, q2, g2, be2, out);
}